// Round 5
// baseline (357.712 us; speedup 1.0000x reference)
//
#include <hip/hip_runtime.h>
#include <hip/hip_bf16.h>
#include <cstdint>
#include <cstddef>

#define T_ 8
#define N_ 16384
#define D_ 512
#define H_ 1024
#define O_ 64
#define IDX_COUNT (T_*N_)   // 131072

typedef __attribute__((ext_vector_type(8))) short short8v;
typedef __attribute__((ext_vector_type(4))) float f32x4;

__device__ __forceinline__ short f2bf(float f) {
  unsigned u = __builtin_bit_cast(unsigned, f);
  u += 0x7fffu + ((u >> 16) & 1u);   // round-to-nearest-even
  return (short)(u >> 16);
}

// ---------------- indices kernel: node_type is sorted repeat(arange(T)) -> indices == arange
__global__ void idx_kernel(float* __restrict__ out) {
  int i = blockIdx.x * 256 + threadIdx.x;
  out[i] = (float)i;
}

// ---------------- prep_w1: W1 f32 -> bf16 lane-linear A-fragment tiles (register-only) ----
// Tile (t,hc,kk) = 16KB: chunk ch = ks*256 + hf*64 + lane; lane = g*16 + r
//   chunk elem e = W1[t][d = kk*128 + ks*32 + g*8 + e][h = hc*64 + hf*16 + r]
__global__ void prep_w1(const float* __restrict__ W1, char* __restrict__ ws) {
  int bid = blockIdx.x;            // t*64 + hc*4 + kk
  int kk = bid & 3, hc = (bid >> 2) & 15, t = bid >> 6;
  int tid = threadIdx.x;
  char* dst = ws + (size_t)bid * 16384;
  const float* src = W1 + ((size_t)t*D_ + kk*128)*H_ + hc*64;
#pragma unroll
  for (int i = 0; i < 4; i++) {
    int ch = i*256 + tid;          // 1024 16B chunks
    int lane = ch & 63, hf = (ch >> 6) & 3, ks = ch >> 8;
    int r = lane & 15, g = lane >> 4;
    short8v p;
#pragma unroll
    for (int e = 0; e < 8; e++)
      p[e] = f2bf(src[(size_t)(ks*32 + g*8 + e)*H_ + hf*16 + r]);
    *(short8v*)(dst + ch*16) = p;
  }
}

// ---------------- prep_w2: W2 f32 -> bf16 A-frags, k scrambled to match in-lane H pack ----
// Chunk (t,hc) = 8KB: ch = kb*256 + of*64 + lane; elem e = m*4+j
//   value = W2[t][h = hc*64 + kb*32 + m*16 + g*4 + j][o = of*16 + r]
__global__ void prep_w2(const float* __restrict__ W2, char* __restrict__ ws) {
  int bid = blockIdx.x;            // t*16 + hc
  int hc = bid & 15, t = bid >> 4;
  int tid = threadIdx.x;
  char* dst = ws + (size_t)bid * 8192;
  const float* src = W2 + ((size_t)t*H_ + hc*64)*O_;
#pragma unroll
  for (int i = 0; i < 2; i++) {
    int ch = i*256 + tid;          // 512 16B chunks
    int lane = ch & 63, of = (ch >> 6) & 3, kb = ch >> 8;
    int r = lane & 15, g = lane >> 4;
    short8v p;
#pragma unroll
    for (int e = 0; e < 8; e++) {
      int m = e >> 2, j = e & 3;
      p[e] = f2bf(src[(size_t)(kb*32 + m*16 + g*4 + j)*O_ + of*16 + r]);
    }
    *(short8v*)(dst + ch*16) = p;
  }
}

// ---------------- fused GEMM1 -> sigmoid -> GEMM2 (swapped operands) ----------------
__device__ __forceinline__ void gl_lds16(const void* g, void* l) {
  __builtin_amdgcn_global_load_lds((const __attribute__((address_space(1))) unsigned int*)g,
                                   (__attribute__((address_space(3))) unsigned int*)l, 16, 0, 0);
}

// 256 threads / 4 waves / 128 rows per block.
// min-waves=1: per-wave unified budget 512 regs -> allocator can hold xf (128 arch) +
// hacc/oacc (64 accum) + temps with ZERO spills. R3/R4's min-waves=2 capped the unified
// budget at 256, the compiler split it 128 arch + 128 acc, and xf alone filled the arch
// file -> 53 MB/launch scratch traffic (WRITE_SIZE 87 MB vs 34 MB ideal).
__global__ __launch_bounds__(256, 1) void gemm_fused(
    const float* __restrict__ x, const float* __restrict__ b1,
    const float* __restrict__ b2, const char* __restrict__ wsw1,
    const char* __restrict__ wsw2, float* __restrict__ out)
{
  __shared__ __align__(16) char w1buf[2][16384];   // W1 tile double buffer
  __shared__ __align__(16) char w2buf[2][8192];    // W2 chunk double buffer

  const int tid = threadIdx.x;
  const int lane = tid & 63;
  const int w = tid >> 6;                  // wave 0..3, owns 32 rows
  // XCD swizzle: 1024 blocks -> one type per XCD (W1_t 1MB stays L2-resident)
  const int bid = ((blockIdx.x & 7) << 7) | (blockIdx.x >> 3);
  const int t = bid >> 7;
  const int rblk = bid & 127;              // 128 row-blocks of 128 rows per type
  const int r = lane & 15;
  const int g = lane >> 4;

  const char* w1base = wsw1 + (size_t)t * (64*16384);
  const char* w2base = wsw2 + (size_t)t * (16*8192);

  // prologue: stage W1 tile 0 + W2 chunk 0 (issued first; they fly under the x loads)
#pragma unroll
  for (int s = 0; s < 4; s++)
    gl_lds16(w1base + s*4096 + tid*16, &w1buf[0][s*4096 + w*1024]);
#pragma unroll
  for (int s = 0; s < 2; s++)
    gl_lds16(w2base + s*4096 + tid*16, &w2buf[0][s*4096 + w*1024]);

  // x rows -> persistent B-fragments (bf16), read exactly once, coalesced.
  // xf[nf][ki]: lane holds x[n = rblk*128 + w*32 + nf*16 + r][d = ki*32 + g*8 + e]
  short8v xf[2][16];
#pragma unroll
  for (int nf = 0; nf < 2; nf++) {
    const float* xr = x + ((size_t)(t*N_ + rblk*128 + w*32 + nf*16 + r))*D_ + g*8;
#pragma unroll
    for (int ki = 0; ki < 16; ki++) {
      const f32x4* p = (const f32x4*)(xr + ki*32);
      f32x4 v0 = p[0], v1 = p[1];
      short8v a;
      a[0]=f2bf(v0[0]); a[1]=f2bf(v0[1]); a[2]=f2bf(v0[2]); a[3]=f2bf(v0[3]);
      a[4]=f2bf(v1[0]); a[5]=f2bf(v1[1]); a[6]=f2bf(v1[2]); a[7]=f2bf(v1[3]);
      xf[nf][ki] = a;
    }
  }

  f32x4 oacc[4][2];   // O^T frags [of][nf]: lane o = of*16+g*4+j, n = nf*16+r
#pragma unroll
  for (int i = 0; i < 4; i++)
#pragma unroll
    for (int nf = 0; nf < 2; nf++) oacc[i][nf] = (f32x4){0.f,0.f,0.f,0.f};

  __syncthreads();   // prologue staging drained

  for (int hc = 0; hc < 16; hc++) {
    f32x4 hacc[4][2];  // H^T frags [hf][nf]: lane h = hf*16+g*4+j, n = nf*16+r
#pragma unroll
    for (int i = 0; i < 4; i++)
#pragma unroll
      for (int nf = 0; nf < 2; nf++) hacc[i][nf] = (f32x4){0.f,0.f,0.f,0.f};

#pragma unroll
    for (int kk = 0; kk < 4; kk++) {
      const int tt = hc*4 + kk;
      if (tt < 63) {                          // prefetch next W1 tile (other parity buffer)
        const char* gsrc = w1base + (size_t)(tt+1)*16384;
        char* nb = &w1buf[(kk+1)&1][0];
#pragma unroll
        for (int s = 0; s < 4; s++)
          gl_lds16(gsrc + s*4096 + tid*16, nb + s*4096 + w*1024);
      }
      if (kk == 1 && hc < 15) {               // W2 prefetch: after kk0-barrier, so GEMM2(hc-1)
        char* nb = &w2buf[(hc+1)&1][0];       // readers of this buffer are provably done
#pragma unroll
        for (int s = 0; s < 2; s++)
          gl_lds16(w2base + (size_t)(hc+1)*8192 + s*4096 + tid*16, nb + s*4096 + w*1024);
      }
      const char* curw1 = &w1buf[kk&1][0];
#pragma unroll
      for (int ks = 0; ks < 4; ks++)
#pragma unroll
        for (int hf = 0; hf < 4; hf++) {
          // lane-linear conflict-free 16B fragment read
          short8v wf = *(const short8v*)(curw1 + (((ks*4 + hf)*64 + lane) << 4));
          hacc[hf][0] = __builtin_amdgcn_mfma_f32_16x16x32_bf16(wf, xf[0][kk*4+ks], hacc[hf][0], 0,0,0);
          hacc[hf][1] = __builtin_amdgcn_mfma_f32_16x16x32_bf16(wf, xf[1][kk*4+ks], hacc[hf][1], 0,0,0);
        }
      __syncthreads();   // next tile staged + this tile's readers done
    }

    // bias + sigmoid + in-lane bf16 pack: H^T D-frag -> GEMM2 B-frag (no LDS round trip)
    const float* b1p = b1 + t*H_ + hc*64;
    short8v hb[2][2];   // [kb][nf]; elem e=m*4+j holds h = kb*32 + m*16 + g*4 + j
#pragma unroll
    for (int hf = 0; hf < 4; hf++) {
      const int kb = hf >> 1, m = hf & 1;
      f32x4 bv = *(const f32x4*)(b1p + hf*16 + g*4);
#pragma unroll
      for (int nf = 0; nf < 2; nf++)
#pragma unroll
        for (int j = 0; j < 4; j++) {
          float v = hacc[hf][nf][j] + bv[j];
          float s = 1.f / (1.f + __expf(-v));
          hb[kb][nf][m*4 + j] = f2bf(s);
        }
    }

    // GEMM2: O^T += W2^T(scrambled-k) . H^T  (k-permutation cancels between operands)
    const char* curw2 = (hc & 1) ? &w2buf[1][0] : &w2buf[0][0];
#pragma unroll
    for (int kb = 0; kb < 2; kb++)
#pragma unroll
      for (int of = 0; of < 4; of++) {
        short8v wf = *(const short8v*)(curw2 + (((kb*4 + of)*64 + lane) << 4));
        oacc[of][0] = __builtin_amdgcn_mfma_f32_16x16x32_bf16(wf, hb[kb][0], oacc[of][0], 0,0,0);
        oacc[of][1] = __builtin_amdgcn_mfma_f32_16x16x32_bf16(wf, hb[kb][1], oacc[of][1], 0,0,0);
      }
  }

  // epilogue: direct f32x4 stores, no LDS. Lane (r,g) owns 4 consecutive floats per row;
  // 4 lanes (g=0..3) fill each 64B line -> line-granular coalescing.
  const float* b2p = b2 + t*O_;
  float* obase = out + IDX_COUNT + ((size_t)(t*N_ + rblk*128 + w*32))*O_;
#pragma unroll
  for (int nf = 0; nf < 2; nf++)
#pragma unroll
    for (int of = 0; of < 4; of++) {
      f32x4 bv = *(const f32x4*)(b2p + of*16 + g*4);
      f32x4 v;
#pragma unroll
      for (int j = 0; j < 4; j++) v[j] = oacc[of][nf][j] + bv[j];
      *(f32x4*)(obase + (size_t)(nf*16 + r)*O_ + of*16 + g*4) = v;
    }
}

// ---------------- naive f32 fallback (only if ws too small) ----------------
__global__ void naive_kernel(const float* __restrict__ x, const float* __restrict__ W1,
                             const float* __restrict__ b1, const float* __restrict__ W2,
                             const float* __restrict__ b2, float* __restrict__ out) {
  const int row = blockIdx.x;
  const int t = row >> 14;
  __shared__ float xs[512];
  __shared__ float hs[1024];
  const float* xr = x + (size_t)row * D_;
  for (int i = threadIdx.x; i < D_; i += 256) xs[i] = xr[i];
  __syncthreads();
  const float* w1t = W1 + (size_t)t * D_ * H_;
  for (int h = threadIdx.x; h < H_; h += 256) {
    float acc = b1[t*H_ + h];
    for (int k = 0; k < D_; k++) acc += xs[k] * w1t[(size_t)k*H_ + h];
    hs[h] = 1.f / (1.f + __expf(-acc));
  }
  __syncthreads();
  const float* w2t = W2 + (size_t)t * H_ * O_;
  for (int o = threadIdx.x; o < O_; o += 256) {
    float acc = b2[t*O_ + o];
    for (int k = 0; k < H_; k++) acc += hs[k] * w2t[k*O_ + o];
    out[IDX_COUNT + (size_t)row*O_ + o] = acc;
  }
}

extern "C" void kernel_launch(void* const* d_in, const int* in_sizes, int n_in,
                              void* d_out, int out_size, void* d_ws, size_t ws_size,
                              hipStream_t stream) {
  const float* x  = (const float*)d_in[0];
  const float* W1 = (const float*)d_in[1];
  const float* b1 = (const float*)d_in[2];
  const float* W2 = (const float*)d_in[3];
  const float* b2 = (const float*)d_in[4];
  float* out = (float*)d_out;

  idx_kernel<<<IDX_COUNT/256, 256, 0, stream>>>(out);

  const size_t w1_bytes = (size_t)T_*64*16384;   // 8,388,608
  const size_t w2_bytes = (size_t)T_*16*8192;    // 1,048,576
  if (ws_size >= w1_bytes + w2_bytes) {
    char* wsw1 = (char*)d_ws;
    char* wsw2 = wsw1 + w1_bytes;
    prep_w1<<<T_*64, 256, 0, stream>>>(W1, wsw1);
    prep_w2<<<T_*16, 256, 0, stream>>>(W2, wsw2);
    gemm_fused<<<T_*(N_/128), 256, 0, stream>>>(x, b1, b2, wsw1, wsw2, out);
  } else {
    naive_kernel<<<T_*N_, 256, 0, stream>>>(x, W1, b1, W2, b2, out);
  }
}

// Round 6
// 254.233 us; speedup vs baseline: 1.4070x; 1.4070x over previous
//
#include <hip/hip_runtime.h>
#include <hip/hip_bf16.h>
#include <cstdint>
#include <cstddef>

#define T_ 8
#define N_ 16384
#define D_ 512
#define H_ 1024
#define O_ 64
#define IDX_COUNT (T_*N_)   // 131072

typedef __attribute__((ext_vector_type(8))) short short8v;
typedef __attribute__((ext_vector_type(4))) float f32x4;

__device__ __forceinline__ short f2bf(float f) {
  unsigned u = __builtin_bit_cast(unsigned, f);
  u += 0x7fffu + ((u >> 16) & 1u);   // round-to-nearest-even
  return (short)(u >> 16);
}

// MFMA with explicit register classes (gfx950 unified RF: A/B/C/D may be VGPR or AGPR).
// GEMM1: D/C in VGPR (sigmoid needs VALU access), B (x-fragment) pinned in AGPR.
__device__ __forceinline__ void mfma_vb_a(f32x4& acc, short8v a_v, short8v b_a) {
  asm("v_mfma_f32_16x16x32_bf16 %0, %1, %2, %0"
      : "+v"(acc) : "v"(a_v), "a"(b_a));
}
// GEMM2: D/C (persistent O accumulator) and B (h-fragment) pinned in AGPR.
__device__ __forceinline__ void mfma_ab_a(f32x4& acc, short8v a_v, short8v b_a) {
  asm("v_mfma_f32_16x16x32_bf16 %0, %1, %2, %0"
      : "+a"(acc) : "v"(a_v), "a"(b_a));
}

// ---------------- indices kernel: node_type is sorted repeat(arange(T)) -> indices == arange
__global__ void idx_kernel(float* __restrict__ out) {
  int i = blockIdx.x * 256 + threadIdx.x;
  out[i] = (float)i;
}

// ---------------- prep_w1: W1 f32 -> bf16 lane-linear A-fragment tiles (register-only) ----
// Tile (t,hc,kk) = 16KB: chunk ch = ks*256 + hf*64 + lane; lane = g*16 + r
//   chunk elem e = W1[t][d = kk*128 + ks*32 + g*8 + e][h = hc*64 + hf*16 + r]
__global__ void prep_w1(const float* __restrict__ W1, char* __restrict__ ws) {
  int bid = blockIdx.x;            // t*64 + hc*4 + kk
  int kk = bid & 3, hc = (bid >> 2) & 15, t = bid >> 6;
  int tid = threadIdx.x;
  char* dst = ws + (size_t)bid * 16384;
  const float* src = W1 + ((size_t)t*D_ + kk*128)*H_ + hc*64;
#pragma unroll
  for (int i = 0; i < 4; i++) {
    int ch = i*256 + tid;          // 1024 16B chunks
    int lane = ch & 63, hf = (ch >> 6) & 3, ks = ch >> 8;
    int r = lane & 15, g = lane >> 4;
    short8v p;
#pragma unroll
    for (int e = 0; e < 8; e++)
      p[e] = f2bf(src[(size_t)(ks*32 + g*8 + e)*H_ + hf*16 + r]);
    *(short8v*)(dst + ch*16) = p;
  }
}

// ---------------- prep_w2: W2 f32 -> bf16 A-frags, k scrambled to match in-lane H pack ----
// Chunk (t,hc) = 8KB: ch = kb*256 + of*64 + lane; elem e = m*4+j
//   value = W2[t][h = hc*64 + kb*32 + m*16 + g*4 + j][o = of*16 + r]
__global__ void prep_w2(const float* __restrict__ W2, char* __restrict__ ws) {
  int bid = blockIdx.x;            // t*16 + hc
  int hc = bid & 15, t = bid >> 4;
  int tid = threadIdx.x;
  char* dst = ws + (size_t)bid * 8192;
  const float* src = W2 + ((size_t)t*H_ + hc*64)*O_;
#pragma unroll
  for (int i = 0; i < 2; i++) {
    int ch = i*256 + tid;          // 512 16B chunks
    int lane = ch & 63, of = (ch >> 6) & 3, kb = ch >> 8;
    int r = lane & 15, g = lane >> 4;
    short8v p;
#pragma unroll
    for (int e = 0; e < 8; e++) {
      int m = e >> 2, j = e & 3;
      p[e] = f2bf(src[(size_t)(kb*32 + m*16 + g*4 + j)*O_ + of*16 + r]);
    }
    *(short8v*)(dst + ch*16) = p;
  }
}

// ---------------- fused GEMM1 -> sigmoid -> GEMM2 (swapped operands) ----------------
__device__ __forceinline__ void gl_lds16(const void* g, void* l) {
  __builtin_amdgcn_global_load_lds((const __attribute__((address_space(1))) unsigned int*)g,
                                   (__attribute__((address_space(3))) unsigned int*)l, 16, 0, 0);
}

// 256 threads / 4 waves / 128 rows per block; min 2 waves/EU -> 256 unified regs/wave.
// Register-class plan (inline-asm constraints): AGPR holds xf(128) + oacc(32) + hb(16) = 176;
// arch VGPR holds hacc(32) + wf/addresses/temps ~ 80. R4's compiler-chosen 128/128 split
// spilled xf (53 MB scratch traffic); R5's (256,1) fit but ran 1 wave/SIMD (12% occupancy).
__global__ __launch_bounds__(256, 2) void gemm_fused(
    const float* __restrict__ x, const float* __restrict__ b1,
    const float* __restrict__ b2, const char* __restrict__ wsw1,
    const char* __restrict__ wsw2, float* __restrict__ out)
{
  __shared__ __align__(16) char w1buf[2][16384];   // W1 tile double buffer
  __shared__ __align__(16) char w2buf[2][8192];    // W2 chunk double buffer

  const int tid = threadIdx.x;
  const int lane = tid & 63;
  const int w = tid >> 6;                  // wave 0..3, owns 32 rows
  // XCD swizzle: 1024 blocks -> one type per XCD (W1_t 1MB stays L2-resident)
  const int bid = ((blockIdx.x & 7) << 7) | (blockIdx.x >> 3);
  const int t = bid >> 7;
  const int rblk = bid & 127;              // 128 row-blocks of 128 rows per type
  const int r = lane & 15;
  const int g = lane >> 4;

  const char* w1base = wsw1 + (size_t)t * (64*16384);
  const char* w2base = wsw2 + (size_t)t * (16*8192);

  // prologue: stage W1 tile 0 + W2 chunk 0 (issued first; they fly under the x loads)
#pragma unroll
  for (int s = 0; s < 4; s++)
    gl_lds16(w1base + s*4096 + tid*16, &w1buf[0][s*4096 + w*1024]);
#pragma unroll
  for (int s = 0; s < 2; s++)
    gl_lds16(w2base + s*4096 + tid*16, &w2buf[0][s*4096 + w*1024]);

  // x rows -> persistent B-fragments (bf16), read exactly once, coalesced.
  // xf[nf][ki]: lane holds x[n = rblk*128 + w*32 + nf*16 + r][d = ki*32 + g*8 + e]
  // All MFMA uses carry an "a" constraint -> allocator homes xf in AGPRs.
  short8v xf[2][16];
#pragma unroll
  for (int nf = 0; nf < 2; nf++) {
    const float* xr = x + ((size_t)(t*N_ + rblk*128 + w*32 + nf*16 + r))*D_ + g*8;
#pragma unroll
    for (int ki = 0; ki < 16; ki++) {
      const f32x4* p = (const f32x4*)(xr + ki*32);
      f32x4 v0 = p[0], v1 = p[1];
      short8v a;
      a[0]=f2bf(v0[0]); a[1]=f2bf(v0[1]); a[2]=f2bf(v0[2]); a[3]=f2bf(v0[3]);
      a[4]=f2bf(v1[0]); a[5]=f2bf(v1[1]); a[6]=f2bf(v1[2]); a[7]=f2bf(v1[3]);
      xf[nf][ki] = a;
    }
  }

  f32x4 oacc[4][2];   // O^T frags [of][nf] (AGPR via "+a"): lane o = of*16+g*4+j, n = nf*16+r
#pragma unroll
  for (int i = 0; i < 4; i++)
#pragma unroll
    for (int nf = 0; nf < 2; nf++) oacc[i][nf] = (f32x4){0.f,0.f,0.f,0.f};

  __syncthreads();   // prologue staging drained

  for (int hc = 0; hc < 16; hc++) {
    f32x4 hacc[4][2];  // H^T frags [hf][nf] (VGPR): lane h = hf*16+g*4+j, n = nf*16+r
#pragma unroll
    for (int i = 0; i < 4; i++)
#pragma unroll
      for (int nf = 0; nf < 2; nf++) hacc[i][nf] = (f32x4){0.f,0.f,0.f,0.f};

#pragma unroll
    for (int kk = 0; kk < 4; kk++) {
      const int tt = hc*4 + kk;
      if (tt < 63) {                          // prefetch next W1 tile (other parity buffer)
        const char* gsrc = w1base + (size_t)(tt+1)*16384;
        char* nb = &w1buf[(kk+1)&1][0];
#pragma unroll
        for (int s = 0; s < 4; s++)
          gl_lds16(gsrc + s*4096 + tid*16, nb + s*4096 + w*1024);
      }
      if (kk == 1 && hc < 15) {               // W2 prefetch: after kk0-barrier, so GEMM2(hc-1)
        char* nb = &w2buf[(hc+1)&1][0];       // readers of this buffer are provably done
#pragma unroll
        for (int s = 0; s < 2; s++)
          gl_lds16(w2base + (size_t)(hc+1)*8192 + s*4096 + tid*16, nb + s*4096 + w*1024);
      }
      const char* curw1 = &w1buf[kk&1][0];
#pragma unroll
      for (int ks = 0; ks < 4; ks++)
#pragma unroll
        for (int hf = 0; hf < 4; hf++) {
          // lane-linear conflict-free 16B fragment read
          short8v wf = *(const short8v*)(curw1 + (((ks*4 + hf)*64 + lane) << 4));
          mfma_vb_a(hacc[hf][0], wf, xf[0][kk*4+ks]);
          mfma_vb_a(hacc[hf][1], wf, xf[1][kk*4+ks]);
        }
      __syncthreads();   // next tile staged + this tile's readers done
    }

    // bias + sigmoid + in-lane bf16 pack: H^T D-frag -> GEMM2 B-frag (no LDS round trip)
    const float* b1p = b1 + t*H_ + hc*64;
    short8v hb[2][2];   // [kb][nf] (AGPR via "a" use); elem e=m*4+j holds h = kb*32+m*16+g*4+j
#pragma unroll
    for (int hf = 0; hf < 4; hf++) {
      const int kb = hf >> 1, m = hf & 1;
      f32x4 bv = *(const f32x4*)(b1p + hf*16 + g*4);
#pragma unroll
      for (int nf = 0; nf < 2; nf++)
#pragma unroll
        for (int j = 0; j < 4; j++) {
          float v = hacc[hf][nf][j] + bv[j];
          float s = 1.f / (1.f + __expf(-v));
          hb[kb][nf][m*4 + j] = f2bf(s);
        }
    }

    // GEMM2: O^T += W2^T(scrambled-k) . H^T  (k-permutation cancels between operands)
    const char* curw2 = (hc & 1) ? &w2buf[1][0] : &w2buf[0][0];
#pragma unroll
    for (int kb = 0; kb < 2; kb++)
#pragma unroll
      for (int of = 0; of < 4; of++) {
        short8v wf = *(const short8v*)(curw2 + (((kb*4 + of)*64 + lane) << 4));
        mfma_ab_a(oacc[of][0], wf, hb[kb][0]);
        mfma_ab_a(oacc[of][1], wf, hb[kb][1]);
      }
  }

  // epilogue: direct f32x4 stores, no LDS. Lane (r,g) owns 4 consecutive floats per row;
  // 4 lanes (g=0..3) fill each 64B line -> line-granular coalescing.
  const float* b2p = b2 + t*O_;
  float* obase = out + IDX_COUNT + ((size_t)(t*N_ + rblk*128 + w*32))*O_;
#pragma unroll
  for (int nf = 0; nf < 2; nf++)
#pragma unroll
    for (int of = 0; of < 4; of++) {
      f32x4 bv = *(const f32x4*)(b2p + of*16 + g*4);
      f32x4 acc = oacc[of][nf];   // AGPR -> VGPR copies inserted by compiler
      f32x4 v;
#pragma unroll
      for (int j = 0; j < 4; j++) v[j] = acc[j] + bv[j];
      *(f32x4*)(obase + (size_t)(nf*16 + r)*O_ + of*16 + g*4) = v;
    }
}

// ---------------- naive f32 fallback (only if ws too small) ----------------
__global__ void naive_kernel(const float* __restrict__ x, const float* __restrict__ W1,
                             const float* __restrict__ b1, const float* __restrict__ W2,
                             const float* __restrict__ b2, float* __restrict__ out) {
  const int row = blockIdx.x;
  const int t = row >> 14;
  __shared__ float xs[512];
  __shared__ float hs[1024];
  const float* xr = x + (size_t)row * D_;
  for (int i = threadIdx.x; i < D_; i += 256) xs[i] = xr[i];
  __syncthreads();
  const float* w1t = W1 + (size_t)t * D_ * H_;
  for (int h = threadIdx.x; h < H_; h += 256) {
    float acc = b1[t*H_ + h];
    for (int k = 0; k < D_; k++) acc += xs[k] * w1t[(size_t)k*H_ + h];
    hs[h] = 1.f / (1.f + __expf(-acc));
  }
  __syncthreads();
  const float* w2t = W2 + (size_t)t * H_ * O_;
  for (int o = threadIdx.x; o < O_; o += 256) {
    float acc = b2[t*O_ + o];
    for (int k = 0; k < H_; k++) acc += hs[k] * w2t[k*O_ + o];
    out[IDX_COUNT + (size_t)row*O_ + o] = acc;
  }
}

extern "C" void kernel_launch(void* const* d_in, const int* in_sizes, int n_in,
                              void* d_out, int out_size, void* d_ws, size_t ws_size,
                              hipStream_t stream) {
  const float* x  = (const float*)d_in[0];
  const float* W1 = (const float*)d_in[1];
  const float* b1 = (const float*)d_in[2];
  const float* W2 = (const float*)d_in[3];
  const float* b2 = (const float*)d_in[4];
  float* out = (float*)d_out;

  idx_kernel<<<IDX_COUNT/256, 256, 0, stream>>>(out);

  const size_t w1_bytes = (size_t)T_*64*16384;   // 8,388,608
  const size_t w2_bytes = (size_t)T_*16*8192;    // 1,048,576
  if (ws_size >= w1_bytes + w2_bytes) {
    char* wsw1 = (char*)d_ws;
    char* wsw2 = wsw1 + w1_bytes;
    prep_w1<<<T_*64, 256, 0, stream>>>(W1, wsw1);
    prep_w2<<<T_*16, 256, 0, stream>>>(W2, wsw2);
    gemm_fused<<<T_*(N_/128), 256, 0, stream>>>(x, b1, b2, wsw1, wsw2, out);
  } else {
    naive_kernel<<<T_*N_, 256, 0, stream>>>(x, W1, b1, W2, b2, out);
  }
}

// Round 7
// 196.183 us; speedup vs baseline: 1.8234x; 1.2959x over previous
//
#include <hip/hip_runtime.h>
#include <hip/hip_bf16.h>
#include <cstdint>
#include <cstddef>

#define T_ 8
#define N_ 16384
#define D_ 512
#define H_ 1024
#define O_ 64
#define IDX_COUNT (T_*N_)   // 131072

typedef __attribute__((ext_vector_type(4))) float f32x4;

#define WSCALE 64.0f        // weights pre-scaled into fp8 normal range
#define INV_WSCALE 0.015625f

// pack 8 floats -> 8 fp8 e4m3 (RNE, saturating) in one 64-bit value, byte e = elem e
__device__ __forceinline__ long long pack8fp8(f32x4 a, f32x4 b) {
  int lo = __builtin_amdgcn_cvt_pk_fp8_f32(a[0], a[1], 0, false);
  lo     = __builtin_amdgcn_cvt_pk_fp8_f32(a[2], a[3], lo, true);
  int hi = __builtin_amdgcn_cvt_pk_fp8_f32(b[0], b[1], 0, false);
  hi     = __builtin_amdgcn_cvt_pk_fp8_f32(b[2], b[3], hi, true);
  return (long long)(unsigned)lo | ((long long)hi << 32);
}

// ---------------- indices kernel: node_type is sorted repeat(arange(T)) -> indices == arange
__global__ void idx_kernel(float* __restrict__ out) {
  int i = blockIdx.x * 256 + threadIdx.x;
  out[i] = (float)i;
}

// ---------------- prep_w1: W1 f32 -> fp8 lane-linear A-fragment tiles ----------------
// Tile (t,hc,kk) = 8KB: chunk ch = (ks*4+hf)*64 + lane (8B); lane = g*16+r
//   chunk elem e = W1[t][d = kk*128+ks*32+g*8+e][h = hc*64+hf*16+r] * WSCALE
__global__ void prep_w1(const float* __restrict__ W1, char* __restrict__ ws) {
  int bid = blockIdx.x;            // t*64 + hc*4 + kk
  int kk = bid & 3, hc = (bid >> 2) & 15, t = bid >> 6;
  int tid = threadIdx.x;
  char* dst = ws + (size_t)bid * 8192;
  const float* src = W1 + ((size_t)t*D_ + kk*128)*H_ + hc*64;
#pragma unroll
  for (int i = 0; i < 4; i++) {
    int ch = i*256 + tid;          // 1024 8B chunks
    int lane = ch & 63, hf = (ch >> 6) & 3, ks = ch >> 8;
    int r = lane & 15, g = lane >> 4;
    f32x4 a, b;
#pragma unroll
    for (int e = 0; e < 4; e++) {
      a[e] = src[(size_t)(ks*32 + g*8 + e)*H_ + hf*16 + r] * WSCALE;
      b[e] = src[(size_t)(ks*32 + g*8 + 4 + e)*H_ + hf*16 + r] * WSCALE;
    }
    *(long long*)(dst + ch*8) = pack8fp8(a, b);
  }
}

// ---------------- prep_w2: W2 f32 -> fp8 A-frags, k scrambled to match in-lane H pack ----
// Chunk (t,hc) = 4KB: ch = (kb*4+of)*64 + lane (8B); elem e = m*4+j
//   value = W2[t][h = hc*64 + kb*32 + m*16 + g*4 + j][o = of*16 + r] * WSCALE
__global__ void prep_w2(const float* __restrict__ W2, char* __restrict__ ws) {
  int bid = blockIdx.x;            // t*16 + hc
  int hc = bid & 15, t = bid >> 4;
  int tid = threadIdx.x;
  char* dst = ws + (size_t)bid * 4096;
  const float* src = W2 + ((size_t)t*H_ + hc*64)*O_;
#pragma unroll
  for (int i = 0; i < 2; i++) {
    int ch = i*256 + tid;          // 512 8B chunks
    int lane = ch & 63, of = (ch >> 6) & 3, kb = ch >> 8;
    int r = lane & 15, g = lane >> 4;
    f32x4 a, b;
#pragma unroll
    for (int j = 0; j < 4; j++) {
      a[j] = src[(size_t)(kb*32 +      g*4 + j)*O_ + of*16 + r] * WSCALE;   // m=0
      b[j] = src[(size_t)(kb*32 + 16 + g*4 + j)*O_ + of*16 + r] * WSCALE;   // m=1
    }
    *(long long*)(dst + ch*8) = pack8fp8(a, b);
  }
}

// ---------------- fused GEMM1 -> sigmoid -> GEMM2 (swapped operands, fp8) ----------------
__device__ __forceinline__ void gl_lds16(const void* g, void* l) {
  __builtin_amdgcn_global_load_lds((const __attribute__((address_space(1))) unsigned int*)g,
                                   (__attribute__((address_space(3))) unsigned int*)l, 16, 0, 0);
}

// 256 threads / 4 waves / 128 rows per block; 2 waves/EU (256 unified regs/wave).
// fp8 shrinks xf to 64 regs: total ~180 fits with ZERO spills, intrinsics only.
__global__ __launch_bounds__(256, 2) void gemm_fused(
    const float* __restrict__ x, const float* __restrict__ b1,
    const float* __restrict__ b2, const char* __restrict__ wsw1,
    const char* __restrict__ wsw2, float* __restrict__ out)
{
  __shared__ __align__(16) char w1buf[2][16384];   // double buffer: PAIR of 8KB W1 tiles
  __shared__ __align__(16) char w2buf[2][4096];    // W2 chunk double buffer

  const int tid = threadIdx.x;
  const int lane = tid & 63;
  const int w = tid >> 6;                  // wave 0..3, owns 32 rows
  // XCD swizzle: 1024 blocks -> one type per XCD (W1_t fp8 = 0.5MB stays L2-resident)
  const int bid = ((blockIdx.x & 7) << 7) | (blockIdx.x >> 3);
  const int t = bid >> 7;
  const int rblk = bid & 127;              // 128 row-blocks of 128 rows per type
  const int r = lane & 15;
  const int g = lane >> 4;

  const char* w1base = wsw1 + (size_t)t * (64*8192);   // 32 pairs of 16KB
  const char* w2base = wsw2 + (size_t)t * (16*4096);

  // prologue: stage W1 pair 0 + W2 chunk 0
#pragma unroll
  for (int s = 0; s < 4; s++)
    gl_lds16(w1base + s*4096 + tid*16, &w1buf[0][s*4096 + w*1024]);
  gl_lds16(w2base + tid*16, &w2buf[0][w*1024]);

  // x rows -> persistent fp8 B-fragments, read exactly once, coalesced.
  // xf[nf][ki]: lane holds x[n = rblk*128 + w*32 + nf*16 + r][d = ki*32 + g*8 + e]
  long long xf[2][16];
#pragma unroll
  for (int nf = 0; nf < 2; nf++) {
    const float* xr = x + ((size_t)(t*N_ + rblk*128 + w*32 + nf*16 + r))*D_ + g*8;
#pragma unroll
    for (int ki = 0; ki < 16; ki++) {
      const f32x4* p = (const f32x4*)(xr + ki*32);
      xf[nf][ki] = pack8fp8(p[0], p[1]);
    }
  }

  f32x4 oacc[4][2];   // O^T frags [of][nf]: lane o = of*16+g*4+j, n = nf*16+r
#pragma unroll
  for (int i = 0; i < 4; i++)
#pragma unroll
    for (int nf = 0; nf < 2; nf++) oacc[i][nf] = (f32x4){0.f,0.f,0.f,0.f};

  __syncthreads();   // prologue staging drained

  for (int hc = 0; hc < 16; hc++) {
    f32x4 hacc[4][2];  // H^T frags [hf][nf]: lane h = hf*16+g*4+j, n = nf*16+r
#pragma unroll
    for (int i = 0; i < 4; i++)
#pragma unroll
      for (int nf = 0; nf < 2; nf++) hacc[i][nf] = (f32x4){0.f,0.f,0.f,0.f};

#pragma unroll
    for (int kp = 0; kp < 2; kp++) {
      const int pp = hc*2 + kp;               // pair index 0..31
      if (pp < 31) {                          // prefetch next W1 pair (other parity buffer)
        const char* gsrc = w1base + (size_t)(pp+1)*16384;
        char* nb = &w1buf[(pp+1)&1][0];
#pragma unroll
        for (int s = 0; s < 4; s++)
          gl_lds16(gsrc + s*4096 + tid*16, nb + s*4096 + w*1024);
      }
      if (kp == 1 && hc < 15)                 // W2 prefetch: after kp0 barrier -> GEMM2(hc-1)
        gl_lds16(w2base + (size_t)(hc+1)*4096 + tid*16, &w2buf[(hc+1)&1][0] + w*1024);

      const char* cur = &w1buf[pp&1][0];
#pragma unroll
      for (int kk2 = 0; kk2 < 2; kk2++)
#pragma unroll
        for (int ks = 0; ks < 4; ks++) {
          const int ki = kp*8 + kk2*4 + ks;   // K-step 0..15
#pragma unroll
          for (int hf = 0; hf < 4; hf++) {
            // lane-linear conflict-free 8B fragment read
            long long wf = *(const long long*)(cur + kk2*8192 + (((ks*4 + hf)*64 + lane) << 3));
            hacc[hf][0] = __builtin_amdgcn_mfma_f32_16x16x32_fp8_fp8(wf, xf[0][ki], hacc[hf][0], 0,0,0);
            hacc[hf][1] = __builtin_amdgcn_mfma_f32_16x16x32_fp8_fp8(wf, xf[1][ki], hacc[hf][1], 0,0,0);
          }
        }
      __syncthreads();   // next pair staged + this pair's readers done
    }

    // bias + sigmoid (un-scale fused) + in-lane fp8 pack: H^T D-frag -> GEMM2 B-frag
    const float* b1p = b1 + t*H_ + hc*64;
    f32x4 sg[4][2];
#pragma unroll
    for (int hf = 0; hf < 4; hf++) {
      f32x4 bv = *(const f32x4*)(b1p + hf*16 + g*4);
#pragma unroll
      for (int nf = 0; nf < 2; nf++)
#pragma unroll
        for (int j = 0; j < 4; j++) {
          float v = hacc[hf][nf][j] * INV_WSCALE + bv[j];
          sg[hf][nf][j] = 1.f / (1.f + __expf(-v));
        }
    }
    long long hb[2][2];   // [kb][nf]; byte e=m*4+j holds h = kb*32 + m*16 + g*4 + j
#pragma unroll
    for (int kb = 0; kb < 2; kb++)
#pragma unroll
      for (int nf = 0; nf < 2; nf++)
        hb[kb][nf] = pack8fp8(sg[2*kb][nf], sg[2*kb+1][nf]);

    // GEMM2: O^T += W2^T(scrambled-k) . H^T  (k-permutation cancels between operands)
    const char* curw2 = (hc & 1) ? &w2buf[1][0] : &w2buf[0][0];
#pragma unroll
    for (int kb = 0; kb < 2; kb++)
#pragma unroll
      for (int of = 0; of < 4; of++) {
        long long wf = *(const long long*)(curw2 + (((kb*4 + of)*64 + lane) << 3));
        oacc[of][0] = __builtin_amdgcn_mfma_f32_16x16x32_fp8_fp8(wf, hb[kb][0], oacc[of][0], 0,0,0);
        oacc[of][1] = __builtin_amdgcn_mfma_f32_16x16x32_fp8_fp8(wf, hb[kb][1], oacc[of][1], 0,0,0);
      }
  }

  // epilogue: direct f32x4 stores (un-scale W2), no LDS.
  const float* b2p = b2 + t*O_;
  float* obase = out + IDX_COUNT + ((size_t)(t*N_ + rblk*128 + w*32))*O_;
#pragma unroll
  for (int nf = 0; nf < 2; nf++)
#pragma unroll
    for (int of = 0; of < 4; of++) {
      f32x4 bv = *(const f32x4*)(b2p + of*16 + g*4);
      f32x4 v;
#pragma unroll
      for (int j = 0; j < 4; j++) v[j] = oacc[of][nf][j] * INV_WSCALE + bv[j];
      *(f32x4*)(obase + (size_t)(nf*16 + r)*O_ + of*16 + g*4) = v;
    }
}

// ---------------- naive f32 fallback (only if ws too small) ----------------
__global__ void naive_kernel(const float* __restrict__ x, const float* __restrict__ W1,
                             const float* __restrict__ b1, const float* __restrict__ W2,
                             const float* __restrict__ b2, float* __restrict__ out) {
  const int row = blockIdx.x;
  const int t = row >> 14;
  __shared__ float xs[512];
  __shared__ float hs[1024];
  const float* xr = x + (size_t)row * D_;
  for (int i = threadIdx.x; i < D_; i += 256) xs[i] = xr[i];
  __syncthreads();
  const float* w1t = W1 + (size_t)t * D_ * H_;
  for (int h = threadIdx.x; h < H_; h += 256) {
    float acc = b1[t*H_ + h];
    for (int k = 0; k < D_; k++) acc += xs[k] * w1t[(size_t)k*H_ + h];
    hs[h] = 1.f / (1.f + __expf(-acc));
  }
  __syncthreads();
  const float* w2t = W2 + (size_t)t * H_ * O_;
  for (int o = threadIdx.x; o < O_; o += 256) {
    float acc = b2[t*O_ + o];
    for (int k = 0; k < H_; k++) acc += hs[k] * w2t[k*O_ + o];
    out[IDX_COUNT + (size_t)row*O_ + o] = acc;
  }
}

extern "C" void kernel_launch(void* const* d_in, const int* in_sizes, int n_in,
                              void* d_out, int out_size, void* d_ws, size_t ws_size,
                              hipStream_t stream) {
  const float* x  = (const float*)d_in[0];
  const float* W1 = (const float*)d_in[1];
  const float* b1 = (const float*)d_in[2];
  const float* W2 = (const float*)d_in[3];
  const float* b2 = (const float*)d_in[4];
  float* out = (float*)d_out;

  idx_kernel<<<IDX_COUNT/256, 256, 0, stream>>>(out);

  const size_t w1_bytes = (size_t)T_*64*8192;    // 4,194,304
  const size_t w2_bytes = (size_t)T_*16*4096;    //   524,288
  if (ws_size >= w1_bytes + w2_bytes) {
    char* wsw1 = (char*)d_ws;
    char* wsw2 = wsw1 + w1_bytes;
    prep_w1<<<T_*64, 256, 0, stream>>>(W1, wsw1);
    prep_w2<<<T_*16, 256, 0, stream>>>(W2, wsw2);
    gemm_fused<<<T_*(N_/128), 256, 0, stream>>>(x, b1, b2, wsw1, wsw2, out);
  } else {
    naive_kernel<<<T_*N_, 256, 0, stream>>>(x, W1, b1, W2, b2, out);
  }
}